// Round 8
// baseline (227.122 us; speedup 1.0000x reference)
//
#include <hip/hip_runtime.h>

// DPLSafePolicy: logits[16384,13] = x[16384,2048] @ [Wg|Wp|Wa], 3 softmaxes,
// sparse-T unsafe combine, renormalize -> out[16384,5].
//
// R8 = R7 MEASUREMENT ROUND: gemm_mfma launched TWICE (idempotent; second
// launch recomputes identical out). dur8 - dur7 = duration of one warm-x
// gemm, assumption-free. Discriminates: (a) ~60us -> kernel intrinsically
// slow (not memory); (b) ~20us -> cold-x memory path is the wall;
// (c) ~0us -> harness floor dominates, kernel already immaterial.

typedef __fp16 h2_t __attribute__((ext_vector_type(2)));
typedef __fp16 h4_t __attribute__((ext_vector_type(4)));
typedef __fp16 h8_t __attribute__((ext_vector_type(8)));
typedef float f32x4 __attribute__((ext_vector_type(4)));

__global__ void pack_bfrag(const float* __restrict__ Wg,
                           const float* __restrict__ Wp,
                           const float* __restrict__ Wa,
                           h8_t* __restrict__ bfrag)
{
    const int t = blockIdx.x * 256 + threadIdx.x;   // 0..4095
    const int iter = t >> 6, lane = t & 63;
    const int n = lane & 15, kg = lane >> 4;
    h8_t v;
    #pragma unroll
    for (int j = 0; j < 8; ++j) {
        const int k = iter * 32 + kg * 8 + j;
        float f;
        if (n < 4)       f = Wg[k * 4 + n];
        else if (n < 8)  f = Wp[k * 4 + (n - 4)];
        else if (n < 13) f = Wa[k * 5 + (n - 8)];
        else             f = 0.f;
        v[j] = (__fp16)f;
    }
    bfrag[t] = v;
}

__global__ __launch_bounds__(256, 2)
void gemm_mfma(const float* __restrict__ x,
               const h8_t* __restrict__ bfrag,
               const float* __restrict__ bg, const float* __restrict__ bp,
               const float* __restrict__ ba, float* __restrict__ out)
{
    __shared__ float dt[2][2][16][17];   // [rt2][ks][row][col], 8704 B

    const int tid = threadIdx.x;
    const int w   = tid >> 6;       // wave 0..3
    const int l   = tid & 63;
    const int rt2 = w & 1;          // row-tile within block
    const int ks  = w >> 1;         // K half
    const int row0 = blockIdx.x * 32 + rt2 * 16;
    const int m  = l & 15;          // A row / D col
    const int kg = l >> 4;          // k-group

    const int phase = (blockIdx.x * 4 + w) & 31;

    const float4* xg = (const float4*)x;
    const long base = (long)(row0 + m) * 512 + ks * 256 + kg * 2;  // float4 units
    const h8_t* bf = bfrag + (ks * 32) * 64 + l;

    float4 pa[4], pb[4];
    h8_t   pf[4];
    #pragma unroll
    for (int d = 0; d < 4; ++d) {
        const int idx = (phase + d) & 31;
        pa[d] = xg[base + idx * 8];
        pb[d] = xg[base + idx * 8 + 1];
        pf[d] = bf[idx * 64];
    }

    f32x4 acc = {0.f, 0.f, 0.f, 0.f};

    #pragma unroll 4
    for (int i = 0; i < 32; ++i) {
        const int s = i & 3;
        const float4 xa = pa[s], xb = pb[s];
        const h8_t b8 = pf[s];
        if (i + 4 < 32) {
            const int idx = (phase + i + 4) & 31;
            pa[s] = xg[base + idx * 8];
            pb[s] = xg[base + idx * 8 + 1];
            pf[s] = bf[idx * 64];
        }
        const h2_t a01 = __builtin_amdgcn_cvt_pkrtz(xa.x, xa.y);
        const h2_t a23 = __builtin_amdgcn_cvt_pkrtz(xa.z, xa.w);
        const h2_t a45 = __builtin_amdgcn_cvt_pkrtz(xb.x, xb.y);
        const h2_t a67 = __builtin_amdgcn_cvt_pkrtz(xb.z, xb.w);
        const h4_t alo = __builtin_shufflevector(a01, a23, 0, 1, 2, 3);
        const h4_t ahi = __builtin_shufflevector(a45, a67, 0, 1, 2, 3);
        const h8_t a8  = __builtin_shufflevector(alo, ahi, 0, 1, 2, 3, 4, 5, 6, 7);
        acc = __builtin_amdgcn_mfma_f32_16x16x32_f16(a8, b8, acc, 0, 0, 0);
    }

    #pragma unroll
    for (int r = 0; r < 4; ++r)
        dt[rt2][ks][kg * 4 + r][m] = acc[r];
    __syncthreads();

    if (w < 2 && l < 16) {
        float lg[13];
        #pragma unroll
        for (int c = 0; c < 13; ++c)
            lg[c] = dt[w][0][l][c] + dt[w][1][l][c];

        const float g0 = lg[0] + bg[0], g1 = lg[1] + bg[1], g2 = lg[2] + bg[2], g3 = lg[3] + bg[3];
        const float q0 = lg[4] + bp[0], q1 = lg[5] + bp[1], q2 = lg[6] + bp[2], q3 = lg[7] + bp[3];
        const float a0 = lg[8] + ba[0], a1 = lg[9] + ba[1], a2 = lg[10] + ba[2],
                    a3 = lg[11] + ba[3], a4 = lg[12] + ba[4];

        float mx, sum, inv;
        mx = fmaxf(fmaxf(g0, g1), fmaxf(g2, g3));
        const float eg0 = __expf(g0 - mx), eg1 = __expf(g1 - mx), eg2 = __expf(g2 - mx), eg3 = __expf(g3 - mx);
        sum = eg0 + eg1 + eg2 + eg3; inv = 1.f / sum;
        const float G0 = eg0 * inv, G1 = eg1 * inv, G2 = eg2 * inv, G3 = eg3 * inv;

        mx = fmaxf(fmaxf(q0, q1), fmaxf(q2, q3));
        const float ep0 = __expf(q0 - mx), ep1 = __expf(q1 - mx), ep2 = __expf(q2 - mx), ep3 = __expf(q3 - mx);
        sum = ep0 + ep1 + ep2 + ep3; inv = 1.f / sum;
        const float P0 = ep0 * inv, P1 = ep1 * inv, P2 = ep2 * inv, P3 = ep3 * inv;

        mx = fmaxf(fmaxf(fmaxf(a0, a1), fmaxf(a2, a3)), a4);
        const float ea0 = __expf(a0 - mx), ea1 = __expf(a1 - mx), ea2 = __expf(a2 - mx),
                    ea3 = __expf(a3 - mx), ea4 = __expf(a4 - mx);
        sum = ea0 + ea1 + ea2 + ea3 + ea4; inv = 1.f / sum;
        const float A0 = ea0 * inv, A1 = ea1 * inv, A2 = ea2 * inv, A3 = ea3 * inv, A4 = ea4 * inv;

        const float u0 = P0 * G0 + P1 * G1 + P2 * G2 + P3 * G3;  // stay
        const float u1 = P0 * G1 + P2 * G3;                      // up
        const float u2 = P1 * G0 + P3 * G2;                      // down

        const float j0 = A0 * (1.f - u0), j1 = A1 * (1.f - u1), j2 = A2 * (1.f - u2),
                    j3 = A3, j4 = A4;
        const float isd = 1.f / (j0 + j1 + j2 + j3 + j4);

        float* o = out + (long)(row0 + l) * 5;
        o[0] = j0 * isd; o[1] = j1 * isd; o[2] = j2 * isd; o[3] = j3 * isd; o[4] = j4 * isd;
    }
}

extern "C" void kernel_launch(void* const* d_in, const int* in_sizes, int n_in,
                              void* d_out, int out_size, void* d_ws, size_t ws_size,
                              hipStream_t stream) {
    const float* x  = (const float*)d_in[0];
    const float* Wg = (const float*)d_in[1];
    const float* bg = (const float*)d_in[2];
    const float* Wp = (const float*)d_in[3];
    const float* bp = (const float*)d_in[4];
    const float* Wa = (const float*)d_in[5];
    const float* ba = (const float*)d_in[6];
    float* out = (float*)d_out;

    h8_t* bfrag = (h8_t*)d_ws;   // 64 KB fragment table

    pack_bfrag<<<16, 256, 0, stream>>>(Wg, Wp, Wa, bfrag);
    gemm_mfma<<<512, 256, 0, stream>>>(x, bfrag, bg, bp, ba, out);
    // MEASUREMENT: second identical launch; dur delta vs R7 = one warm-x gemm.
    gemm_mfma<<<512, 256, 0, stream>>>(x, bfrag, bg, bp, ba, out);
}

// Round 9
// 198.328 us; speedup vs baseline: 1.1452x; 1.1452x over previous
//
#include <hip/hip_runtime.h>

// DPLSafePolicy: logits[16384,13] = x[16384,2048] @ [Wg|Wp|Wa], 3 softmaxes,
// sparse-T unsafe combine, renormalize -> out[16384,5].
//
// R9 = R7 + NON-TEMPORAL x loads. R8's double-launch measured warm gemm
// = 22.7 us vs cold = ~60 us: the +37 us is x-read misses allocating into
// an L3 left 100% dirty by the harness's 512 MB ws-poison fill -> forced
// writebacks (~134 read + ~200 writeback MB = ~60 us). x has zero reuse,
// so nt (no-alloc streaming) loads skip L3 allocation and the writeback
// tax: cold gemm should drop to the pure 134 MB HBM read (~21-25 us).
// bfrag keeps normal caching (512x reuse). Everything else = R7.

typedef __fp16 h2_t __attribute__((ext_vector_type(2)));
typedef __fp16 h4_t __attribute__((ext_vector_type(4)));
typedef __fp16 h8_t __attribute__((ext_vector_type(8)));
typedef float f32x4 __attribute__((ext_vector_type(4)));

__global__ void pack_bfrag(const float* __restrict__ Wg,
                           const float* __restrict__ Wp,
                           const float* __restrict__ Wa,
                           h8_t* __restrict__ bfrag)
{
    const int t = blockIdx.x * 256 + threadIdx.x;   // 0..4095
    const int iter = t >> 6, lane = t & 63;
    const int n = lane & 15, kg = lane >> 4;
    h8_t v;
    #pragma unroll
    for (int j = 0; j < 8; ++j) {
        const int k = iter * 32 + kg * 8 + j;
        float f;
        if (n < 4)       f = Wg[k * 4 + n];
        else if (n < 8)  f = Wp[k * 4 + (n - 4)];
        else if (n < 13) f = Wa[k * 5 + (n - 8)];
        else             f = 0.f;
        v[j] = (__fp16)f;
    }
    bfrag[t] = v;
}

__global__ __launch_bounds__(256, 2)
void gemm_mfma(const float* __restrict__ x,
               const h8_t* __restrict__ bfrag,
               const float* __restrict__ bg, const float* __restrict__ bp,
               const float* __restrict__ ba, float* __restrict__ out)
{
    __shared__ float dt[2][2][16][17];   // [rt2][ks][row][col], 8704 B

    const int tid = threadIdx.x;
    const int w   = tid >> 6;       // wave 0..3
    const int l   = tid & 63;
    const int rt2 = w & 1;          // row-tile within block
    const int ks  = w >> 1;         // K half
    const int row0 = blockIdx.x * 32 + rt2 * 16;
    const int m  = l & 15;          // A row / D col
    const int kg = l >> 4;          // k-group

    const int phase = (blockIdx.x * 4 + w) & 31;

    const f32x4* xg = (const f32x4*)x;
    const long base = (long)(row0 + m) * 512 + ks * 256 + kg * 2;  // float4 units
    const h8_t* bf = bfrag + (ks * 32) * 64 + l;

    // 4-deep rotated prefetch; x via nt loads (no L3 alloc -> no dirty
    // poison writeback on the miss path)
    f32x4 pa[4], pb[4];
    h8_t  pf[4];
    #pragma unroll
    for (int d = 0; d < 4; ++d) {
        const int idx = (phase + d) & 31;
        pa[d] = __builtin_nontemporal_load(xg + base + idx * 8);
        pb[d] = __builtin_nontemporal_load(xg + base + idx * 8 + 1);
        pf[d] = bf[idx * 64];
    }

    f32x4 acc = {0.f, 0.f, 0.f, 0.f};

    #pragma unroll 4
    for (int i = 0; i < 32; ++i) {
        const int s = i & 3;
        const f32x4 xa = pa[s], xb = pb[s];
        const h8_t b8 = pf[s];
        if (i + 4 < 32) {
            const int idx = (phase + i + 4) & 31;
            pa[s] = __builtin_nontemporal_load(xg + base + idx * 8);
            pb[s] = __builtin_nontemporal_load(xg + base + idx * 8 + 1);
            pf[s] = bf[idx * 64];
        }
        const h2_t a01 = __builtin_amdgcn_cvt_pkrtz(xa.x, xa.y);
        const h2_t a23 = __builtin_amdgcn_cvt_pkrtz(xa.z, xa.w);
        const h2_t a45 = __builtin_amdgcn_cvt_pkrtz(xb.x, xb.y);
        const h2_t a67 = __builtin_amdgcn_cvt_pkrtz(xb.z, xb.w);
        const h4_t alo = __builtin_shufflevector(a01, a23, 0, 1, 2, 3);
        const h4_t ahi = __builtin_shufflevector(a45, a67, 0, 1, 2, 3);
        const h8_t a8  = __builtin_shufflevector(alo, ahi, 0, 1, 2, 3, 4, 5, 6, 7);
        acc = __builtin_amdgcn_mfma_f32_16x16x32_f16(a8, b8, acc, 0, 0, 0);
    }

    // D-frag: lane l, reg r -> D[row=kg*4+r][col=m]
    #pragma unroll
    for (int r = 0; r < 4; ++r)
        dt[rt2][ks][kg * 4 + r][m] = acc[r];
    __syncthreads();

    // epilogue: waves 0,1 (=row-tile), lanes 0..15 (=row within tile)
    if (w < 2 && l < 16) {
        float lg[13];
        #pragma unroll
        for (int c = 0; c < 13; ++c)
            lg[c] = dt[w][0][l][c] + dt[w][1][l][c];

        const float g0 = lg[0] + bg[0], g1 = lg[1] + bg[1], g2 = lg[2] + bg[2], g3 = lg[3] + bg[3];
        const float q0 = lg[4] + bp[0], q1 = lg[5] + bp[1], q2 = lg[6] + bp[2], q3 = lg[7] + bp[3];
        const float a0 = lg[8] + ba[0], a1 = lg[9] + ba[1], a2 = lg[10] + ba[2],
                    a3 = lg[11] + ba[3], a4 = lg[12] + ba[4];

        float mx, sum, inv;
        mx = fmaxf(fmaxf(g0, g1), fmaxf(g2, g3));
        const float eg0 = __expf(g0 - mx), eg1 = __expf(g1 - mx), eg2 = __expf(g2 - mx), eg3 = __expf(g3 - mx);
        sum = eg0 + eg1 + eg2 + eg3; inv = 1.f / sum;
        const float G0 = eg0 * inv, G1 = eg1 * inv, G2 = eg2 * inv, G3 = eg3 * inv;

        mx = fmaxf(fmaxf(q0, q1), fmaxf(q2, q3));
        const float ep0 = __expf(q0 - mx), ep1 = __expf(q1 - mx), ep2 = __expf(q2 - mx), ep3 = __expf(q3 - mx);
        sum = ep0 + ep1 + ep2 + ep3; inv = 1.f / sum;
        const float P0 = ep0 * inv, P1 = ep1 * inv, P2 = ep2 * inv, P3 = ep3 * inv;

        mx = fmaxf(fmaxf(fmaxf(a0, a1), fmaxf(a2, a3)), a4);
        const float ea0 = __expf(a0 - mx), ea1 = __expf(a1 - mx), ea2 = __expf(a2 - mx),
                    ea3 = __expf(a3 - mx), ea4 = __expf(a4 - mx);
        sum = ea0 + ea1 + ea2 + ea3 + ea4; inv = 1.f / sum;
        const float A0 = ea0 * inv, A1 = ea1 * inv, A2 = ea2 * inv, A3 = ea3 * inv, A4 = ea4 * inv;

        const float u0 = P0 * G0 + P1 * G1 + P2 * G2 + P3 * G3;  // stay
        const float u1 = P0 * G1 + P2 * G3;                      // up
        const float u2 = P1 * G0 + P3 * G2;                      // down

        const float j0 = A0 * (1.f - u0), j1 = A1 * (1.f - u1), j2 = A2 * (1.f - u2),
                    j3 = A3, j4 = A4;
        const float isd = 1.f / (j0 + j1 + j2 + j3 + j4);

        float* o = out + (long)(row0 + l) * 5;
        o[0] = j0 * isd; o[1] = j1 * isd; o[2] = j2 * isd; o[3] = j3 * isd; o[4] = j4 * isd;
    }
}

extern "C" void kernel_launch(void* const* d_in, const int* in_sizes, int n_in,
                              void* d_out, int out_size, void* d_ws, size_t ws_size,
                              hipStream_t stream) {
    const float* x  = (const float*)d_in[0];
    const float* Wg = (const float*)d_in[1];
    const float* bg = (const float*)d_in[2];
    const float* Wp = (const float*)d_in[3];
    const float* bp = (const float*)d_in[4];
    const float* Wa = (const float*)d_in[5];
    const float* ba = (const float*)d_in[6];
    float* out = (float*)d_out;

    h8_t* bfrag = (h8_t*)d_ws;   // 64 KB fragment table

    pack_bfrag<<<16, 256, 0, stream>>>(Wg, Wp, Wa, bfrag);
    gemm_mfma<<<512, 256, 0, stream>>>(x, bfrag, bg, bp, ba, out);
}